// Round 1
// baseline (163.885 us; speedup 1.0000x reference)
//
#include <hip/hip_runtime.h>

#define B_   2
#define L_   2048
#define H_   1024
#define NH_  16
#define KVH_ 4
#define HD_  64

typedef short short8 __attribute__((ext_vector_type(8)));
typedef float f32x4 __attribute__((ext_vector_type(4)));
typedef unsigned short u16x4 __attribute__((ext_vector_type(4)));

static __device__ __forceinline__ unsigned short f2bf(float f) {
  unsigned int u = __float_as_uint(f);
  u += 0x7FFFu + ((u >> 16) & 1u);   // RNE; inputs finite, no NaN handling needed
  return (unsigned short)(u >> 16);
}

static __device__ __forceinline__ void gload_lds16(const unsigned short* g, unsigned short* l) {
  __builtin_amdgcn_global_load_lds(
      (const __attribute__((address_space(1))) unsigned int*)(const void*)g,
      (__attribute__((address_space(3))) unsigned int*)(void*)l, 16, 0, 0);
}

// ---------------- converts ----------------
__global__ __launch_bounds__(256) void k_convert_x(const float* __restrict__ x,
                                                   unsigned short* __restrict__ xb) {
  size_t i = ((size_t)blockIdx.x * 256 + threadIdx.x) * 4;
  float4 v = *(const float4*)(x + i);
  u16x4 o = { f2bf(v.x), f2bf(v.y), f2bf(v.z), f2bf(v.w) };
  *(u16x4*)(xb + i) = o;
}

// rows 0..1023 Wq, 1024..1279 Wk, 1280..1535 Wv -> wcat; 1536..2559 Wo -> wo_b
__global__ __launch_bounds__(256) void k_convert_w(const float* __restrict__ Wq,
                                                   const float* __restrict__ Wk,
                                                   const float* __restrict__ Wv,
                                                   const float* __restrict__ Wo,
                                                   unsigned short* __restrict__ wcat,
                                                   unsigned short* __restrict__ wo_b) {
  int r = blockIdx.x;
  int c = threadIdx.x * 4;
  const float* src;
  unsigned short* dst;
  if (r < 1024)      { src = Wq + (size_t)r * 1024;          dst = wcat + (size_t)r * 1024; }
  else if (r < 1280) { src = Wk + (size_t)(r - 1024) * 1024; dst = wcat + (size_t)r * 1024; }
  else if (r < 1536) { src = Wv + (size_t)(r - 1280) * 1024; dst = wcat + (size_t)r * 1024; }
  else               { src = Wo + (size_t)(r - 1536) * 1024; dst = wo_b + (size_t)(r - 1536) * 1024; }
  float4 v = *(const float4*)(src + c);
  u16x4 o = { f2bf(v.x), f2bf(v.y), f2bf(v.z), f2bf(v.w) };
  *(u16x4*)(dst + c) = o;
}

// ---------------- GEMM: C[M,N] = A[M,K] * Bt[N,K]^T  (m97-style 128x128x32) ----------------
// MODE 0: QKV epilogue (split q/k/vt, bf16). MODE 1: fp32 out + bias0.
template <int MODE>
__global__ __launch_bounds__(256) void k_gemm(const unsigned short* __restrict__ A,
                                              const unsigned short* __restrict__ Bt,
                                              const float* __restrict__ bias0,
                                              const float* __restrict__ bias1,
                                              const float* __restrict__ bias2,
                                              unsigned short* __restrict__ q_ws,
                                              unsigned short* __restrict__ k_ws,
                                              unsigned short* __restrict__ vt_ws,
                                              float* __restrict__ outp) {
  const int bn = blockIdx.x, bm = blockIdx.y;
  const int t = threadIdx.x;
  const int lane = t & 63, li = lane & 15, g = lane >> 4;
  const int wid = t >> 6, wr = wid >> 1, wc = wid & 1;
  __shared__ unsigned short lds_a[128 * 32];
  __shared__ unsigned short lds_b[128 * 32];

  const f32x4 z = {0.f, 0.f, 0.f, 0.f};
  f32x4 acc[4][4];
#pragma unroll
  for (int m = 0; m < 4; ++m)
#pragma unroll
    for (int n = 0; n < 4; ++n) acc[m][n] = z;

  const int c0 = t, c1 = 256 + t;
  const int r0 = c0 >> 2, o0 = (c0 & 3) * 8;
  const int r1 = c1 >> 2, o1 = (c1 & 3) * 8;
  const unsigned short* a0p = A + (size_t)(bm * 128 + r0) * 1024 + o0;
  const unsigned short* a1p = A + (size_t)(bm * 128 + r1) * 1024 + o1;
  const unsigned short* b0p = Bt + (size_t)(bn * 128 + r0) * 1024 + o0;
  const unsigned short* b1p = Bt + (size_t)(bn * 128 + r1) * 1024 + o1;

  for (int kt = 0; kt < 1024; kt += 32) {
    gload_lds16(a0p + kt, &lds_a[c0 * 8]);
    gload_lds16(a1p + kt, &lds_a[c1 * 8]);
    gload_lds16(b0p + kt, &lds_b[c0 * 8]);
    gload_lds16(b1p + kt, &lds_b[c1 * 8]);
    __syncthreads();
    short8 af[4], bf[4];
#pragma unroll
    for (int m = 0; m < 4; ++m) af[m] = *(const short8*)&lds_a[(wr * 64 + m * 16 + li) * 32 + g * 8];
#pragma unroll
    for (int n = 0; n < 4; ++n) bf[n] = *(const short8*)&lds_b[(wc * 64 + n * 16 + li) * 32 + g * 8];
#pragma unroll
    for (int m = 0; m < 4; ++m)
#pragma unroll
      for (int n = 0; n < 4; ++n)
        acc[m][n] = __builtin_amdgcn_mfma_f32_16x16x32_bf16(af[m], bf[n], acc[m][n], 0, 0, 0);
    __syncthreads();
  }

#pragma unroll
  for (int m = 0; m < 4; ++m) {
    const int row0 = bm * 128 + wr * 64 + m * 16 + 4 * g;  // D row = 4g+reg
#pragma unroll
    for (int n = 0; n < 4; ++n) {
      const int col = bn * 128 + wc * 64 + n * 16 + li;    // D col = lane&15
      f32x4 v = acc[m][n];
      if (MODE == 1) {
        const float bias = bias0[col];
#pragma unroll
        for (int r = 0; r < 4; ++r) outp[(size_t)(row0 + r) * 1024 + col] = v[r] + bias;
      } else {
        if (col < 1024) {
          const float bias = bias0[col];
#pragma unroll
          for (int r = 0; r < 4; ++r) q_ws[(size_t)(row0 + r) * 1024 + col] = f2bf(v[r] + bias);
        } else if (col < 1280) {
          const int cc = col - 1024;
          const float bias = bias1[cc];
#pragma unroll
          for (int r = 0; r < 4; ++r) k_ws[(size_t)(row0 + r) * 256 + cc] = f2bf(v[r] + bias);
        } else {
          const int cc = col - 1280;
          const float bias = bias2[cc];
          const int kvh = cc >> 6, d = cc & 63;
          const int b = row0 >> 11, l0 = row0 & 2047;
          u16x4 pk = { f2bf(v[0] + bias), f2bf(v[1] + bias), f2bf(v[2] + bias), f2bf(v[3] + bias) };
          *(u16x4*)(vt_ws + ((size_t)((b * KVH_ + kvh) * 64 + d)) * 2048 + l0) = pk;
        }
      }
    }
  }
}

// ---------------- flash attention (GQA) ----------------
// grid (B*NH, L/64). 4 waves x 16 q-rows. KV tile = 64.
// S^T = K * Q^T (softmax axis lane-local); O accumulated as O^T.
__global__ __launch_bounds__(256) void k_attn(const unsigned short* __restrict__ q_ws,
                                              const unsigned short* __restrict__ k_ws,
                                              const unsigned short* __restrict__ vt_ws,
                                              const float* __restrict__ mask,
                                              unsigned short* __restrict__ ctx) {
  const int hb = blockIdx.x;     // b*NH + h
  const int qt = blockIdx.y;     // q tile
  const int b = hb >> 4, h = hb & 15;
  const int kvh = h >> 2;
  const int t = threadIdx.x;
  const int wid = t >> 6, lane = t & 63, li = lane & 15, g = lane >> 4;

  __shared__ unsigned short lds_k[64 * 72];          // [kj][d], +8 pad
  __shared__ unsigned short lds_v[64 * 72];          // [d][kj(l)], +8 pad
  __shared__ unsigned short lds_p[4 * 16 * 72];      // per-wave P [qi][kj]

  const int qrow = qt * 64 + wid * 16 + li;
  const size_t qg = (size_t)b * L_ + qrow;

  const short8 qf0 = *(const short8*)(q_ws + qg * H_ + h * HD_ + g * 8);        // d 0..31
  const short8 qf1 = *(const short8*)(q_ws + qg * H_ + h * HD_ + 32 + g * 8);   // d 32..63

  const f32x4 z = {0.f, 0.f, 0.f, 0.f};
  f32x4 o[4];
#pragma unroll
  for (int d = 0; d < 4; ++d) o[d] = z;
  float m_run = -INFINITY, l_run = 0.f;

  // staging: thread t handles rows (t>>3) and (t>>3)+32, 16B at col (t&7)*8
  const int srow = t >> 3;
  const int soff = (t & 7) * 8;
  const unsigned short* kgp = k_ws + ((size_t)b * L_ + srow) * 256 + kvh * 64 + soff;
  const unsigned short* vgp = vt_ws + ((size_t)(b * KVH_ + kvh) * 64 + srow) * 2048 + soff;
  unsigned short* lk0 = &lds_k[srow * 72 + soff];
  unsigned short* lk1 = &lds_k[(srow + 32) * 72 + soff];
  unsigned short* lv0 = &lds_v[srow * 72 + soff];
  unsigned short* lv1 = &lds_v[(srow + 32) * 72 + soff];
  unsigned short* pw = &lds_p[wid * 1152];

#pragma unroll 1
  for (int kt = 0; kt < 32; ++kt) {
    short8 kv0 = *(const short8*)(kgp + (size_t)kt * 64 * 256);
    short8 kv1 = *(const short8*)(kgp + 32 * 256 + (size_t)kt * 64 * 256);
    short8 vv0 = *(const short8*)(vgp + kt * 64);
    short8 vv1 = *(const short8*)(vgp + 32 * 2048 + kt * 64);
    __syncthreads();            // previous iteration's LDS reads done
    *(short8*)lk0 = kv0;
    *(short8*)lk1 = kv1;
    *(short8*)lv0 = vv0;
    *(short8*)lv1 = vv1;
    __syncthreads();            // tiles visible

    // S^T tiles: A = K rows (lane&15 -> kj), B = Q^T (lane&15 -> qi)
    f32x4 ps[4];
    const float* mrow = mask + ((size_t)b * L_ + qrow) * L_ + kt * 64 + 4 * g;
#pragma unroll
    for (int kb = 0; kb < 4; ++kb) {
      short8 a0 = *(const short8*)&lds_k[(kb * 16 + li) * 72 + g * 8];
      short8 a1 = *(const short8*)&lds_k[(kb * 16 + li) * 72 + 32 + g * 8];
      f32x4 s = z;
      s = __builtin_amdgcn_mfma_f32_16x16x32_bf16(a0, qf0, s, 0, 0, 0);
      s = __builtin_amdgcn_mfma_f32_16x16x32_bf16(a1, qf1, s, 0, 0, 0);
      float4 mv = *(const float4*)(mrow + kb * 16);
      ps[kb][0] = s[0] * 0.125f + mv.x;
      ps[kb][1] = s[1] * 0.125f + mv.y;
      ps[kb][2] = s[2] * 0.125f + mv.z;
      ps[kb][3] = s[3] * 0.125f + mv.w;
    }

    // online softmax (per qi = lane&15; reduce over regs then g-groups)
    float tm = ps[0][0];
#pragma unroll
    for (int kb = 0; kb < 4; ++kb)
#pragma unroll
      for (int r = 0; r < 4; ++r) tm = fmaxf(tm, ps[kb][r]);
    tm = fmaxf(tm, __shfl_xor(tm, 16));
    tm = fmaxf(tm, __shfl_xor(tm, 32));
    const float m_new = fmaxf(m_run, tm);
    const float corr = __expf(m_run - m_new);
    float tsum = 0.f;
#pragma unroll
    for (int kb = 0; kb < 4; ++kb)
#pragma unroll
      for (int r = 0; r < 4; ++r) {
        float p = __expf(ps[kb][r] - m_new);
        ps[kb][r] = p;
        tsum += p;
      }
    tsum += __shfl_xor(tsum, 16);
    tsum += __shfl_xor(tsum, 32);
    l_run = l_run * corr + tsum;
    m_run = m_new;
#pragma unroll
    for (int d = 0; d < 4; ++d) {
      o[d][0] *= corr; o[d][1] *= corr; o[d][2] *= corr; o[d][3] *= corr;
    }

    // P -> LDS [qi][kj] (bf16), then PV: O^T += V^T * P^T
#pragma unroll
    for (int kb = 0; kb < 4; ++kb) {
      u16x4 pk = { f2bf(ps[kb][0]), f2bf(ps[kb][1]), f2bf(ps[kb][2]), f2bf(ps[kb][3]) };
      *(u16x4*)&pw[li * 72 + kb * 16 + 4 * g] = pk;
    }
    asm volatile("s_waitcnt lgkmcnt(0)" ::: "memory");  // cross-lane P RAW within wave
#pragma unroll
    for (int kjh = 0; kjh < 2; ++kjh) {
      short8 pb = *(const short8*)&pw[li * 72 + kjh * 32 + g * 8];
#pragma unroll
      for (int d = 0; d < 4; ++d) {
        short8 va = *(const short8*)&lds_v[(d * 16 + li) * 72 + kjh * 32 + g * 8];
        o[d] = __builtin_amdgcn_mfma_f32_16x16x32_bf16(va, pb, o[d], 0, 0, 0);
      }
    }
  }

  const float inv = 1.0f / l_run;
  unsigned short* cp = ctx + qg * H_ + h * HD_;
#pragma unroll
  for (int d = 0; d < 4; ++d) {
    u16x4 pk = { f2bf(o[d][0] * inv), f2bf(o[d][1] * inv), f2bf(o[d][2] * inv), f2bf(o[d][3] * inv) };
    *(u16x4*)(cp + d * 16 + 4 * g) = pk;
  }
}

// ---------------- launch ----------------
extern "C" void kernel_launch(void* const* d_in, const int* in_sizes, int n_in,
                              void* d_out, int out_size, void* d_ws, size_t ws_size,
                              hipStream_t stream) {
  const float* x    = (const float*)d_in[0];
  const float* mask = (const float*)d_in[1];
  const float* Wq   = (const float*)d_in[2];
  const float* bq   = (const float*)d_in[3];
  const float* Wk   = (const float*)d_in[4];
  const float* bk   = (const float*)d_in[5];
  const float* Wv   = (const float*)d_in[6];
  const float* bv   = (const float*)d_in[7];
  const float* Wo   = (const float*)d_in[8];
  const float* bo   = (const float*)d_in[9];
  float* out = (float*)d_out;

  char* ws = (char*)d_ws;
  unsigned short* xb    = (unsigned short*)(ws);                 // 8 MB (reused as ctx)
  unsigned short* ctx   = xb;                                    // alias: xb dead after QKV gemm
  unsigned short* wcat  = (unsigned short*)(ws + 8388608);       // 3 MB
  unsigned short* wo_b  = (unsigned short*)(ws + 11534336);      // 2 MB
  unsigned short* q_ws  = (unsigned short*)(ws + 13631488);      // 8 MB
  unsigned short* k_ws  = (unsigned short*)(ws + 22020096);      // 2 MB
  unsigned short* vt_ws = (unsigned short*)(ws + 24117248);      // 2 MB  (total 25 MB)

  k_convert_x<<<dim3(4096), dim3(256), 0, stream>>>(x, xb);
  k_convert_w<<<dim3(2560), dim3(256), 0, stream>>>(Wq, Wk, Wv, Wo, wcat, wo_b);
  k_gemm<0><<<dim3(12, 32), dim3(256), 0, stream>>>(xb, wcat, bq, bk, bv, q_ws, k_ws, vt_ws, nullptr);
  k_attn<<<dim3(32, 32), dim3(256), 0, stream>>>(q_ws, k_ws, vt_ws, mask, ctx);
  k_gemm<1><<<dim3(8, 32), dim3(256), 0, stream>>>(ctx, wo_b, bo, nullptr, nullptr,
                                                   nullptr, nullptr, nullptr, out);
}